// Round 1
// baseline (322.358 us; speedup 1.0000x reference)
//
#include <hip/hip_runtime.h>
#include <math.h>

#define N_TOKENS 32768
#define D_MODEL  1024
#define N_EXPERT 16

// d_out layout (float32, concatenated outputs):
//   [0, 65536)            top_k_indices as floats, row-major [N,2]
//   [65536, 131072)       top_k_scores,            row-major [N,2]
//   [131072]              loss scalar
// d_ws layout: 32 floats: [0,16) expert counts, [16,32) prob sums

__global__ __launch_bounds__(256, 4)
void gate_kernel(const float* __restrict__ inp,
                 const float* __restrict__ W,
                 float* __restrict__ out,
                 float* __restrict__ acc)
{
    const int tid  = threadIdx.x;
    const int wave = tid >> 6;
    const int lane = tid & 63;

    // Wave w owns dims [w*256, w*256+256); each lane owns 4 contiguous dims.
    // W fragment lives in 64 VGPRs per lane, loaded once, reused for all tokens.
    const int d0 = wave * 256 + lane * 4;
    float4 wreg[N_EXPERT];
    #pragma unroll
    for (int e = 0; e < N_EXPERT; ++e)
        wreg[e] = *reinterpret_cast<const float4*>(W + e * D_MODEL + d0);

    __shared__ float lds_part[4][N_EXPERT];
    __shared__ float blk_cnt[N_EXPERT];
    __shared__ float blk_psum[N_EXPERT];
    if (tid < N_EXPERT) { blk_cnt[tid] = 0.f; blk_psum[tid] = 0.f; }
    __syncthreads();

    const int iters = N_TOKENS / gridDim.x;
    for (int it = 0; it < iters; ++it) {
        const int tok = blockIdx.x + it * gridDim.x;

        // coalesced: block reads the full 4KB token row (1KB per wave-instr)
        float4 x = *reinterpret_cast<const float4*>(inp + (size_t)tok * D_MODEL + d0);

        float vals[N_EXPERT];
        #pragma unroll
        for (int e = 0; e < N_EXPERT; ++e)
            vals[e] = x.x * wreg[e].x + x.y * wreg[e].y
                    + x.z * wreg[e].z + x.w * wreg[e].w;

        // Butterfly transpose-reduce: after masks 8,4,2,1 each lane holds
        // sum over its 16-lane group of vals[lane&15]; masks 16,32 finish
        // the full 64-lane reduction. 17 shuffles total.
        #pragma unroll
        for (int m = 8; m >= 1; m >>= 1) {
            const bool hi = (lane & m) != 0;
            float nv[8];
            #pragma unroll
            for (int k = 0; k < m; ++k) {
                float mine  = hi ? vals[k + m] : vals[k];
                float other = hi ? vals[k]     : vals[k + m];
                nv[k] = mine + __shfl_xor(other, m);
            }
            #pragma unroll
            for (int k = 0; k < m; ++k) vals[k] = nv[k];
        }
        float r = vals[0];
        r += __shfl_xor(r, 16);
        r += __shfl_xor(r, 32);

        if (lane < N_EXPERT) lds_part[wave][lane] = r;
        __syncthreads();

        if (tid == 0) {
            float logit[N_EXPERT];
            #pragma unroll
            for (int e = 0; e < N_EXPERT; ++e)
                logit[e] = lds_part[0][e] + lds_part[1][e]
                         + lds_part[2][e] + lds_part[3][e];

            // top-2, ties -> lowest index (matches jax.lax.top_k)
            int i1 = 0; float l1 = logit[0];
            #pragma unroll
            for (int e = 1; e < N_EXPERT; ++e)
                if (logit[e] > l1) { l1 = logit[e]; i1 = e; }
            int i2 = -1; float l2 = -INFINITY;
            #pragma unroll
            for (int e = 0; e < N_EXPERT; ++e)
                if (e != i1 && logit[e] > l2) { l2 = logit[e]; i2 = e; }

            // softmax over {l1, l2} (others are -inf -> prob 0)
            float t  = expf(l2 - l1);
            float p1 = 1.f / (1.f + t);
            float p2 = t * p1;

            out[2 * tok]     = (float)i1;
            out[2 * tok + 1] = (float)i2;
            out[2 * N_TOKENS + 2 * tok]     = p1;
            out[2 * N_TOKENS + 2 * tok + 1] = p2;

            blk_cnt[i1] += 1.f; blk_cnt[i2] += 1.f;
            blk_psum[i1] += p1; blk_psum[i2] += p2;
        }
        __syncthreads();
    }

    if (tid < N_EXPERT) {
        atomicAdd(&acc[tid],            blk_cnt[tid]);
        atomicAdd(&acc[N_EXPERT + tid], blk_psum[tid]);
    }
}

__global__ void loss_kernel(const float* __restrict__ acc, float* __restrict__ out)
{
    if (threadIdx.x == 0) {
        float s = 0.f;
        #pragma unroll
        for (int e = 0; e < N_EXPERT; ++e)
            s += acc[e] * acc[N_EXPERT + e];
        // loss = E * sum_i (cnt_i/N) * (psum_i/N)
        out[4 * N_TOKENS] = s * (float)N_EXPERT
                          / ((float)N_TOKENS * (float)N_TOKENS);
    }
}

extern "C" void kernel_launch(void* const* d_in, const int* in_sizes, int n_in,
                              void* d_out, int out_size, void* d_ws, size_t ws_size,
                              hipStream_t stream)
{
    const float* inp = (const float*)d_in[0];
    const float* W   = (const float*)d_in[1];
    float* out = (float*)d_out;
    float* acc = (float*)d_ws;

    hipMemsetAsync(acc, 0, 32 * sizeof(float), stream);
    gate_kernel<<<2048, 256, 0, stream>>>(inp, W, out, acc);
    loss_kernel<<<1, 64, 0, stream>>>(acc, out);
}

// Round 2
// 78.268 us; speedup vs baseline: 4.1186x; 4.1186x over previous
//
#include <hip/hip_runtime.h>
#include <math.h>

#define N_TOKENS 32768
#define D_MODEL  1024
#define N_EXPERT 16
#define TOK_PER_BLK 16
#define NBLK (N_TOKENS / TOK_PER_BLK)   // 2048

// d_out layout (float32, concatenated outputs):
//   [0, 65536)       top_k_indices as floats, row-major [N,2]
//   [65536, 131072)  top_k_scores,            row-major [N,2]
//   [131072]         loss scalar
// d_ws: 32 floats: [0,16) expert counts, [16,32) prob sums

__global__ __launch_bounds__(256, 2)
void gate_kernel(const float* __restrict__ inp,
                 const float* __restrict__ W,
                 float* __restrict__ out,
                 float* __restrict__ acc)
{
    const int tid  = threadIdx.x;
    const int wave = tid >> 6;        // 0..3
    const int lane = tid & 63;
    const int egrp = lane >> 4;       // 0..3
    const int s    = lane & 15;       // dim sub-slice
    const int e    = wave * 4 + egrp; // this lane's expert (phase A)

    const int tok0 = blockIdx.x * TOK_PER_BLK;

    // W fragment in registers: 16 float4 = 64 VGPRs per lane, loaded once.
    // Per k: 4 expert-rows x 16 lanes x 16B contiguous -> coalesced.
    float4 wreg[16];
    #pragma unroll
    for (int k = 0; k < 16; ++k)
        wreg[k] = *reinterpret_cast<const float4*>(W + e * D_MODEL + (k * 16 + s) * 4);

    __shared__ float lds_logit[TOK_PER_BLK][N_EXPERT];
    __shared__ float lds_cnt[TOK_PER_BLK][N_EXPERT];
    __shared__ float lds_ps[TOK_PER_BLK][N_EXPERT];

    float4 xa[16], xb[16];

#define LOADX(buf, t) { \
    const float* xbase = inp + (size_t)(tok0 + (t)) * D_MODEL; \
    _Pragma("unroll") \
    for (int k = 0; k < 16; ++k) \
        buf[k] = *reinterpret_cast<const float4*>(xbase + (k * 16 + s) * 4); \
}

    // Per token: 64 FMAs/lane, then 4-step shuffle reduce over the 16 dim-slices.
#define ACCT(buf, t) { \
    float a0 = 0.f; \
    _Pragma("unroll") \
    for (int k = 0; k < 16; ++k) \
        a0 += buf[k].x * wreg[k].x + buf[k].y * wreg[k].y \
            + buf[k].z * wreg[k].z + buf[k].w * wreg[k].w; \
    a0 += __shfl_xor(a0, 1); \
    a0 += __shfl_xor(a0, 2); \
    a0 += __shfl_xor(a0, 4); \
    a0 += __shfl_xor(a0, 8); \
    if (s == 0) lds_logit[t][e] = a0; \
}

    // Phase A: 16 tokens, no barriers, explicit ping-pong prefetch.
    LOADX(xa, 0)
    #pragma unroll
    for (int t = 0; t < TOK_PER_BLK; t += 2) {
        if (t + 1 < TOK_PER_BLK) { LOADX(xb, t + 1) }
        ACCT(xa, t)
        if (t + 2 < TOK_PER_BLK) { LOADX(xa, t + 2) }
        if (t + 1 < TOK_PER_BLK) { ACCT(xb, t + 1) }
    }

    __syncthreads();

    // Phase B: 16 tokens in parallel; 16 lanes per token do top-2 + softmax.
    {
        const int tgrp = tid >> 4;    // token within block (0..15)
        const int el   = tid & 15;    // expert lane
        float v1 = lds_logit[tgrp][el];
        int   i1 = el;
        float v2 = -INFINITY;
        int   i2 = 0;
        #pragma unroll
        for (int m = 1; m <= 8; m <<= 1) {
            float o1 = __shfl_xor(v1, m);
            int  oi1 = __shfl_xor(i1, m);
            float o2 = __shfl_xor(v2, m);
            int  oi2 = __shfl_xor(i2, m);
            // (val desc, idx asc) ordering — matches jax.lax.top_k ties
            bool afirst = (v1 > o1) || (v1 == o1 && i1 < oi1);
            float c1v = afirst ? v1 : o1;   int c1i = afirst ? i1 : oi1;
            float bv  = afirst ? o1 : v1;   int bi  = afirst ? oi1 : i1;  // loser of firsts
            float sv  = afirst ? v2 : o2;   int si  = afirst ? i2 : oi2;  // winner's own 2nd
            bool sgt  = (bv > sv) || (bv == sv && bi < si);
            v1 = c1v; i1 = c1i;
            v2 = sgt ? bv : sv;  i2 = sgt ? bi : si;
        }
        float tt = expf(v2 - v1);          // v2 <= v1, no overflow
        float p1 = 1.f / (1.f + tt);
        float p2 = tt * p1;
        const int tok = tok0 + tgrp;
        if (el == 0) {
            *reinterpret_cast<float2*>(out + 2 * tok) =
                make_float2((float)i1, (float)i2);
            *reinterpret_cast<float2*>(out + 2 * N_TOKENS + 2 * tok) =
                make_float2(p1, p2);
        }
        lds_cnt[tgrp][el] = (el == i1 ? 1.f : 0.f) + (el == i2 ? 1.f : 0.f);
        lds_ps [tgrp][el] = (el == i1 ? p1 : 0.f) + (el == i2 ? p2 : 0.f);
    }
    __syncthreads();

    // Block-level reduce of counts / prob-sums, then 32 global atomics.
    if (tid < 32) {
        const int el = tid & 15;
        float ssum = 0.f;
        if (tid < 16) {
            #pragma unroll
            for (int g = 0; g < 16; ++g) ssum += lds_cnt[g][el];
            atomicAdd(&acc[el], ssum);
        } else {
            #pragma unroll
            for (int g = 0; g < 16; ++g) ssum += lds_ps[g][el];
            atomicAdd(&acc[N_EXPERT + el], ssum);
        }
    }
#undef LOADX
#undef ACCT
}

__global__ void loss_kernel(const float* __restrict__ acc, float* __restrict__ out)
{
    if (threadIdx.x == 0) {
        float sum = 0.f;
        #pragma unroll
        for (int e = 0; e < N_EXPERT; ++e)
            sum += acc[e] * acc[N_EXPERT + e];
        out[4 * N_TOKENS] = sum * (float)N_EXPERT
                          / ((float)N_TOKENS * (float)N_TOKENS);
    }
}

extern "C" void kernel_launch(void* const* d_in, const int* in_sizes, int n_in,
                              void* d_out, int out_size, void* d_ws, size_t ws_size,
                              hipStream_t stream)
{
    const float* inp = (const float*)d_in[0];
    const float* W   = (const float*)d_in[1];
    float* out = (float*)d_out;
    float* acc = (float*)d_ws;

    hipMemsetAsync(acc, 0, 32 * sizeof(float), stream);
    gate_kernel<<<NBLK, 256, 0, stream>>>(inp, W, out, acc);
    loss_kernel<<<1, 64, 0, stream>>>(acc, out);
}